// Round 1
// baseline (1457.324 us; speedup 1.0000x reference)
//
#include <hip/hip_runtime.h>

#define B_ 16
#define N_ 1024
#define M_ 4096
#define D_ 64
#define SROWS_ (N_ + 63)        // 1087 valid skewed steps per tile
#define SROWSP_ (SROWS_ + 9)    // padded stride (refill overrun safety)
#define SPAIR_ 544              // step-pairs per tile
#define TSB_ ((size_t)SPAIR_ * 128)  // dec bytes per tile (69632)
#define BTQ_ 96                 // backtrack window quads (384 cells)

__device__ __forceinline__ float finf() { return __builtin_inff(); }

__device__ __forceinline__ float wave_shr1(float x) {
  return __int_as_float(__builtin_amdgcn_update_dpp(
      0, __float_as_int(x), 0x138, 0xF, 0xF, false));
}
__device__ __forceinline__ float rdlane(float v, int l) {
  return __int_as_float(__builtin_amdgcn_readlane(__float_as_int(v), l));
}

// ---------------------------------------------------------------------------
__global__ void prep_kernel(const float* __restrict__ x,
                            const float* __restrict__ x_t,
                            float* __restrict__ x2,
                            float* __restrict__ w_ts_out) {
  int id = blockIdx.x * blockDim.x + threadIdx.x;
  const float4* xr = (const float4*)(x + (size_t)id * D_);
  float s = 0.f;
#pragma unroll
  for (int e = 0; e < D_ / 4; ++e) {
    float4 v = xr[e];
    s += v.x * v.x + v.y * v.y + v.z * v.z + v.w * v.w;
  }
  x2[id] = s;
  w_ts_out[id] = x_t[id];
}

// ---------------------------------------------------------------------------
// GEMM writing C pre-skewed per 256-col tile: Cs[tile][(i+l)*256 + ct], l=ct>>2.
// ---------------------------------------------------------------------------
__global__ __launch_bounds__(256) void gemm_kernel(
    const float* __restrict__ x, const float* __restrict__ y,
    const float* __restrict__ x2, float* __restrict__ Cs, int chunkBase) {
  const int b = blockIdx.z;
  const int tile = blockIdx.x;
  const int lane = threadIdx.x & 63;
  const int wid = threadIdx.x >> 6;
  const int ct = wid * 64 + lane;
  const int j = chunkBase + tile * 256 + ct;
  const int l = ct >> 2;
  float* CsT = Cs + (size_t)(b * 4 + tile) * SROWSP_ * 256;

  const float4* yrow = (const float4*)(y + ((size_t)b * M_ + j) * D_);
  float4 yr[D_ / 4];
#pragma unroll
  for (int e = 0; e < D_ / 4; ++e) yr[e] = yrow[e];
  float y2 = 0.f;
#pragma unroll
  for (int e = 0; e < D_ / 4; ++e)
    y2 += yr[e].x * yr[e].x + yr[e].y * yr[e].y + yr[e].z * yr[e].z + yr[e].w * yr[e].w;

  const int ibeg = blockIdx.y * 128;
  for (int i = ibeg; i < ibeg + 128; ++i) {
    const float4* xr = (const float4*)(x + ((size_t)b * N_ + i) * D_);
    float acc = 0.f;
#pragma unroll
    for (int e = 0; e < D_ / 4; ++e) {
      float4 xv = xr[e];
      acc += xv.x * yr[e].x + xv.y * yr[e].y + xv.z * yr[e].z + xv.w * yr[e].w;
    }
    CsT[(size_t)(i + l) * 256 + ct] = x2[b * N_ + i] + y2 - 2.f * acc;
  }
}

// ---------------------------------------------------------------------------
// Systolic DP, one batch per 256-thread WG (1 wave/SIMD). Wave W owns a
// 256-col tile; lane l owns 4 cols; step s => row i = s - lane. DECOUPLED
// pipeline: full-column (1024-entry) LDS edge buffer per wave pair, producer
// publishes batched (8 rows, lane 63, block end), consumer polls once/block
// with ~8 blocks of slack. dec packed as ushort (2 steps/store).
// ---------------------------------------------------------------------------
__global__ __launch_bounds__(256) void dtw_dp(
    const float* __restrict__ Cs, unsigned char* __restrict__ dec,
    const float* __restrict__ carryIn, float* __restrict__ carryOut,
    float* __restrict__ partV, int* __restrict__ partJ,
    int chunk, int hasCarry) {
  const int b = blockIdx.x;
  const int t = threadIdx.x;
  const int lane = t & 63;
  const int W = t >> 6;

  __shared__ float ring[3][1024];
  __shared__ float cring[1024];
  __shared__ int prog[3];
  __shared__ float redV[4];
  __shared__ int redJ[4];
  volatile int* vProg = prog;

  if (t < 3) prog[t] = -1;
  const float* cIn = carryIn + b * N_;
  if (hasCarry) ((float4*)cring)[t] = ((const float4*)cIn)[t];
  __syncthreads();

  const float INF = finf();
  const float* loadP = Cs + (size_t)(b * 4 + W) * SROWSP_ * 256;
  const int tileG = chunk * 4 + W;
  unsigned short* decP =
      (unsigned short*)(dec + (size_t)(b * 16 + tileG) * TSB_) + lane;
  float* carryB = carryOut + b * N_;
  const int jbase = tileG * 256 + lane * 4;

  float4 cc0 = ((const float4*)(loadP + 0 * 256))[lane];
  float4 cc1 = ((const float4*)(loadP + 1 * 256))[lane];
  float4 cc2 = ((const float4*)(loadP + 2 * 256))[lane];
  float4 cc3 = ((const float4*)(loadP + 3 * 256))[lane];
  float4 cc4 = ((const float4*)(loadP + 4 * 256))[lane];
  float4 cc5 = ((const float4*)(loadP + 5 * 256))[lane];
  float4 cc6 = ((const float4*)(loadP + 6 * 256))[lane];
  float4 cc7 = ((const float4*)(loadP + 7 * 256))[lane];
  loadP += 8 * 256;

  float edgeVec = INF, lvPrev = INF;
  float up0 = 0.f, up1 = 0.f, up2 = 0.f, up3 = 0.f;
  float dpp1 = INF, dpp2 = INF;
  float fin0 = INF, fin1 = INF, fin2 = INF, fin3 = INF;
  float ebuf[8];

#define BLOCKHEAD()                                                           \
  {                                                                           \
    if (W > 0) {                                                              \
      if (sb < N_) {                                                          \
        const int tgt = sb + 7;                                               \
        while (vProg[W - 1] < tgt) {}                                         \
        asm volatile("" ::: "memory");                                        \
        lvPrev = rdlane(edgeVec, 7);                                          \
        edgeVec = ring[W - 1][(sb + lane) & 1023];                            \
      }                                                                       \
    } else if (hasCarry) {                                                    \
      lvPrev = rdlane(edgeVec, 7);                                            \
      if (sb < N_) edgeVec = cring[(sb + lane) & 1023];                       \
    }                                                                         \
  }

#define DPSTEP(KK, CCV, ROW0, FIN)                                            \
  {                                                                           \
    const float lv = rdlane(edgeVec, (KK));                                   \
    const float left = (lane == 0) ? lv : dpp1;                               \
    const float diag = (lane == 0) ? lvPrev : dpp2;                           \
    lvPrev = lv;                                                              \
    float m0 = fminf(up0, left);                                              \
    float bv0 = fminf(diag, m0);                                              \
    unsigned int pk = (diag <= m0) ? 0u : ((up0 <= left) ? 1u : 2u);          \
    if (ROW0) bv0 = (sb + (KK) == lane) ? 0.f : bv0;                          \
    const float D0 = CCV.x + bv0;                                             \
    float m1 = fminf(up1, D0);                                                \
    float bv1 = fminf(up0, m1);                                               \
    pk |= ((up0 <= m1) ? 0u : ((up1 <= D0) ? 1u : 2u)) << 2;                  \
    if (ROW0) bv1 = (sb + (KK) == lane) ? 0.f : bv1;                          \
    const float D1 = CCV.y + bv1;                                             \
    float m2 = fminf(up2, D1);                                                \
    float bv2 = fminf(up1, m2);                                               \
    pk |= ((up1 <= m2) ? 0u : ((up2 <= D1) ? 1u : 2u)) << 4;                  \
    if (ROW0) bv2 = (sb + (KK) == lane) ? 0.f : bv2;                          \
    const float D2 = CCV.z + bv2;                                             \
    float m3 = fminf(up3, D2);                                                \
    float bv3 = fminf(up2, m3);                                               \
    pk |= ((up2 <= m3) ? 0u : ((up3 <= D2) ? 1u : 2u)) << 6;                  \
    if (ROW0) bv3 = (sb + (KK) == lane) ? 0.f : bv3;                          \
    const float D3 = CCV.w + bv3;                                             \
    ebuf[(KK)] = D3;                                                          \
    if ((KK) & 1) {                                                           \
      pk16 |= pk << 8;                                                        \
      decP[((KK) >> 1) * 64] = (unsigned short)pk16;                          \
    } else {                                                                  \
      pk16 = pk;                                                              \
    }                                                                         \
    if (FIN) {                                                                \
      const bool lr = (sb + (KK) == 1023 + lane);                             \
      fin0 = lr ? D0 : fin0; fin1 = lr ? D1 : fin1;                           \
      fin2 = lr ? D2 : fin2; fin3 = lr ? D3 : fin3;                           \
    }                                                                         \
    const float sh = wave_shr1(D3);                                           \
    dpp2 = dpp1; dpp1 = sh;                                                   \
    up0 = D0; up1 = D1; up2 = D2; up3 = D3;                                   \
    CCV = ((const float4*)(loadP + (KK) * 256))[lane];                        \
  }

#define BLOCKEND()                                                            \
  {                                                                           \
    const int r0 = sb - 63;                                                   \
    if (W < 3) {                                                              \
      if (lane == 63 && r0 > -8 && r0 < N_) {                                 \
        _Pragma("unroll") for (int k = 0; k < 8; ++k) {                       \
          const int r = r0 + k;                                               \
          if ((unsigned)r < (unsigned)N_) ring[W][r] = ebuf[k];               \
        }                                                                     \
        __builtin_amdgcn_s_waitcnt(0xC07F);                                   \
        vProg[W] = r0 + 7;                                                    \
      }                                                                       \
    } else if (chunk < 3) {                                                   \
      if (lane == 63 && r0 > -8 && r0 < N_) {                                 \
        _Pragma("unroll") for (int k = 0; k < 8; ++k) {                       \
          const int r = r0 + k;                                               \
          if ((unsigned)r < (unsigned)N_) carryB[r] = ebuf[k];                \
        }                                                                     \
      }                                                                       \
    }                                                                         \
    loadP += 8 * 256;                                                         \
    decP += 256;                                                              \
  }

#define STEP8(R0, FN)                                                         \
  DPSTEP(0, cc0, R0, FN) DPSTEP(1, cc1, R0, FN) DPSTEP(2, cc2, R0, FN)        \
  DPSTEP(3, cc3, R0, FN) DPSTEP(4, cc4, R0, FN) DPSTEP(5, cc5, R0, FN)        \
  DPSTEP(6, cc6, R0, FN) DPSTEP(7, cc7, R0, FN)

  int sb = 0;
  for (; sb < 64; sb += 8) {   // prologue: row-0 selects live
    BLOCKHEAD();
    unsigned int pk16;
    STEP8(1, 0)
    BLOCKEND();
  }
  for (; sb < 1016; sb += 8) { // main
    BLOCKHEAD();
    unsigned int pk16;
    STEP8(0, 0)
    BLOCKEND();
  }
  for (; sb < 1088; sb += 8) { // epilogue: fin captures
    BLOCKHEAD();
    unsigned int pk16;
    STEP8(0, 1)
    BLOCKEND();
  }
#undef DPSTEP
#undef STEP8
#undef BLOCKHEAD
#undef BLOCKEND

  float mv = fin0; int mj = jbase;
  if (fin1 < mv) { mv = fin1; mj = jbase + 1; }
  if (fin2 < mv) { mv = fin2; mj = jbase + 2; }
  if (fin3 < mv) { mv = fin3; mj = jbase + 3; }
#pragma unroll
  for (int off = 32; off > 0; off >>= 1) {
    const float ov = __shfl_down(mv, off);
    const int oj = __shfl_down(mj, off);
    if (ov < mv || (ov == mv && oj < mj)) { mv = ov; mj = oj; }
  }
  if (lane == 0) { redV[W] = mv; redJ[W] = mj; }
  __syncthreads();
  if (t == 0) {
    float bm = redV[0]; int bj = redJ[0];
#pragma unroll
    for (int w = 1; w < 4; ++w)
      if (redV[w] < bm) { bm = redV[w]; bj = redJ[w]; }
    partV[b * 4 + chunk] = bm;
    partJ[b * 4 + chunk] = bj;
  }
}

// ---------------------------------------------------------------------------
// Backtrack over skewed ushort-packed dec. Byte for (row r, quad q):
// tile=q>>6, l=q&63, s=r+l -> tile*TSB + (s>>1)*128 + l*2 + (s&1).
// ---------------------------------------------------------------------------
__global__ __launch_bounds__(64) void backtrack_kernel(
    const unsigned char* __restrict__ dec, const float* __restrict__ partV,
    const int* __restrict__ partJ, int nch, const float* __restrict__ y_t,
    float* __restrict__ w_vs, float* __restrict__ cost_out) {
  const int b = blockIdx.x;
  const int lane = threadIdx.x;
  __shared__ unsigned char win[64][BTQ_ + 4];
  __shared__ unsigned short tab[64][BTQ_ * 4 + 2];
  __shared__ int st_i, st_j;
  __shared__ int jrow[65];
  const unsigned char* db = dec + (size_t)b * 16 * TSB_;
  const float* yt = y_t + b * M_;
  float* wv = w_vs + b * N_;

  if (lane == 0) {
    float bc = finf(); int bj = 0;
    for (int c = 0; c < nch; ++c) {
      const float v = partV[b * nch + c];
      const int j = partJ[b * nch + c];
      if (v < bc) { bc = v; bj = j; }
    }
    cost_out[b] = bc;
    st_i = N_ - 1;
    st_j = bj;
    wv[N_ - 1] = yt[bj];
  }
  for (;;) {
    __syncthreads();
    const int i = st_i, j = st_j;
    if (i <= 0) break;
    const int qj = j >> 2;
    int qlo = qj - (BTQ_ - 1);
    if (qlo < 0) qlo = 0;
    const int r = i - lane;
    if (r >= 1) {
      for (int k = 0; k < BTQ_; ++k) {
        const int q = qlo + k;
        const int l = q & 63;
        const int s = r + l;
        win[lane][k] =
            db[(size_t)(q >> 6) * TSB_ + (size_t)(s >> 1) * 128 + l * 2 + (s & 1)];
      }
      unsigned short run = 0xFFFF;  // stuck sentinel
      for (int k = 0; k < BTQ_; ++k) {
        const unsigned int byte = win[lane][k];
#pragma unroll
        for (int cs = 0; cs < 4; ++cs) {
          const unsigned int code = (byte >> (2 * cs)) & 3u;
          const int c = 4 * k + cs;
          const unsigned short v =
              (code != 2u) ? (unsigned short)((c << 2) | code) : run;
          tab[lane][c] = v;
          run = v;
        }
      }
    }
    __syncthreads();
    if (lane == 0) {
      const int base = qlo << 2;
      int rr = i, cj = j;
      while (rr >= 1 && (i - rr) < 64) {
        const int l = i - rr;
        const int c = cj - base;
        if (c < 0) break;
        const unsigned short v = tab[l][c];
        if (v == 0xFFFF) { cj = base - 1; break; }
        const int e = v >> 2;
        const int ce = v & 3;
        cj = base + e - (ce == 0 ? 1 : 0);
        --rr;
        jrow[i - rr] = cj;
      }
      st_i = rr;
      st_j = cj;
    }
    __syncthreads();
    const int cnt = i - st_i;
    if (lane < cnt) wv[i - 1 - lane] = yt[jrow[lane + 1]];
  }
}

// ---------------------------------------------------------------------------
extern "C" void kernel_launch(void* const* d_in, const int* in_sizes, int n_in,
                              void* d_out, int out_size, void* d_ws, size_t ws_size,
                              hipStream_t stream) {
  const float* x = (const float*)d_in[0];
  const float* y = (const float*)d_in[1];
  const float* x_t = (const float*)d_in[2];
  const float* y_t = (const float*)d_in[3];

  float* out_cost = (float*)d_out;      // [B_]
  float* out_wts = out_cost + B_;       // [B_][N_]
  float* out_wvs = out_wts + B_ * N_;   // [B_][N_]

  const size_t csBytes = (size_t)B_ * 4 * SROWSP_ * 256 * 4;  // ~71.9 MB
  const size_t decBytes = (size_t)B_ * 16 * TSB_;             // ~17.8 MB
  const size_t x2Bytes = (size_t)B_ * N_ * 4;

  char* ws = (char*)d_ws;
  float* Cs = (float*)ws;
  unsigned char* dec = (unsigned char*)(ws + csBytes);
  float* x2 = (float*)(ws + csBytes + decBytes);
  float* carryA = (float*)(ws + csBytes + decBytes + x2Bytes);
  float* carryB = carryA + B_ * N_;
  float* partV = carryB + B_ * N_;
  int* partJ = (int*)(partV + B_ * 4);

  prep_kernel<<<dim3((B_ * N_) / 256), 256, 0, stream>>>(x, x_t, x2, out_wts);

  float* cbuf[2] = {carryA, carryB};
  for (int c = 0; c < 4; ++c) {
    gemm_kernel<<<dim3(4, N_ / 128, B_), 256, 0, stream>>>(x, y, x2, Cs,
                                                           c * 1024);
    const float* cin = cbuf[(c + 1) & 1];
    float* cout = cbuf[c & 1];
    dtw_dp<<<dim3(B_), 256, 0, stream>>>(Cs, dec, cin, cout, partV, partJ, c,
                                         c > 0 ? 1 : 0);
  }

  backtrack_kernel<<<dim3(B_), 64, 0, stream>>>(dec, partV, partJ, 4, y_t,
                                                out_wvs, out_cost);
}

// Round 2
// 1377.132 us; speedup vs baseline: 1.0582x; 1.0582x over previous
//
#include <hip/hip_runtime.h>

#define B_ 16
#define N_ 1024
#define M_ 4096
#define D_ 64
#define SROWS_ (N_ + 63)        // 1087 valid skewed steps per tile
#define SROWSP_ (SROWS_ + 9)    // padded stride (refill overrun safety)
#define SPAIR_ 544              // step-pairs per tile
#define TSB_ ((size_t)SPAIR_ * 128)  // dec bytes per tile (69632)
#define BTQ_ 96                 // backtrack window quads (384 cells)

__device__ __forceinline__ float finf() { return __builtin_inff(); }

__device__ __forceinline__ float wave_shr1(float x) {
  return __int_as_float(__builtin_amdgcn_update_dpp(
      0, __float_as_int(x), 0x138, 0xF, 0xF, false));
}
__device__ __forceinline__ float rdlane(float v, int l) {
  return __int_as_float(__builtin_amdgcn_readlane(__float_as_int(v), l));
}

// ---------------------------------------------------------------------------
__global__ void prep_kernel(const float* __restrict__ x,
                            const float* __restrict__ x_t,
                            float* __restrict__ x2,
                            float* __restrict__ w_ts_out) {
  int id = blockIdx.x * blockDim.x + threadIdx.x;
  const float4* xr = (const float4*)(x + (size_t)id * D_);
  float s = 0.f;
#pragma unroll
  for (int e = 0; e < D_ / 4; ++e) {
    float4 v = xr[e];
    s += v.x * v.x + v.y * v.y + v.z * v.z + v.w * v.w;
  }
  x2[id] = s;
  w_ts_out[id] = x_t[id];
}

// ---------------------------------------------------------------------------
// GEMM writing C pre-skewed per 256-col tile: Cs[tile][(i+l)*256 + ct], l=ct>>2.
// ---------------------------------------------------------------------------
__global__ __launch_bounds__(256) void gemm_kernel(
    const float* __restrict__ x, const float* __restrict__ y,
    const float* __restrict__ x2, float* __restrict__ Cs, int chunkBase) {
  const int b = blockIdx.z;
  const int tile = blockIdx.x;
  const int lane = threadIdx.x & 63;
  const int wid = threadIdx.x >> 6;
  const int ct = wid * 64 + lane;
  const int j = chunkBase + tile * 256 + ct;
  const int l = ct >> 2;
  float* CsT = Cs + (size_t)(b * 4 + tile) * SROWSP_ * 256;

  const float4* yrow = (const float4*)(y + ((size_t)b * M_ + j) * D_);
  float4 yr[D_ / 4];
#pragma unroll
  for (int e = 0; e < D_ / 4; ++e) yr[e] = yrow[e];
  float y2 = 0.f;
#pragma unroll
  for (int e = 0; e < D_ / 4; ++e)
    y2 += yr[e].x * yr[e].x + yr[e].y * yr[e].y + yr[e].z * yr[e].z + yr[e].w * yr[e].w;

  const int ibeg = blockIdx.y * 128;
  for (int i = ibeg; i < ibeg + 128; ++i) {
    const float4* xr = (const float4*)(x + ((size_t)b * N_ + i) * D_);
    float acc = 0.f;
#pragma unroll
    for (int e = 0; e < D_ / 4; ++e) {
      float4 xv = xr[e];
      acc += xv.x * yr[e].x + xv.y * yr[e].y + xv.z * yr[e].z + xv.w * yr[e].w;
    }
    CsT[(size_t)(i + l) * 256 + ct] = x2[b * N_ + i] + y2 - 2.f * acc;
  }
}

// ---------------------------------------------------------------------------
// Systolic DP, one batch per 256-thread WG (1 wave/SIMD). Wave W owns a
// 256-col tile; lane l owns 4 cols; step s => row i = s - lane. DECOUPLED
// pipeline: full-column (1024-entry) LDS edge buffer per wave pair, producer
// publishes batched (8 rows, lane 63, block end), consumer polls once/block
// with ~8 blocks of slack. dec packed as ushort (2 steps/store).
// ---------------------------------------------------------------------------
__global__ __launch_bounds__(256) void dtw_dp(
    const float* __restrict__ Cs, unsigned char* __restrict__ dec,
    const float* __restrict__ carryIn, float* __restrict__ carryOut,
    float* __restrict__ partV, int* __restrict__ partJ,
    int chunk, int hasCarry) {
  const int b = blockIdx.x;
  const int t = threadIdx.x;
  const int lane = t & 63;
  const int W = t >> 6;

  __shared__ float ring[3][1024];
  __shared__ float cring[1024];
  __shared__ int prog[3];
  __shared__ float redV[4];
  __shared__ int redJ[4];
  volatile int* vProg = prog;

  if (t < 3) prog[t] = -1;
  const float* cIn = carryIn + b * N_;
  if (hasCarry) ((float4*)cring)[t] = ((const float4*)cIn)[t];
  __syncthreads();

  const float INF = finf();
  const float* loadP = Cs + (size_t)(b * 4 + W) * SROWSP_ * 256;
  const int tileG = chunk * 4 + W;
  unsigned short* decP =
      (unsigned short*)(dec + (size_t)(b * 16 + tileG) * TSB_) + lane;
  float* carryB = carryOut + b * N_;
  const int jbase = tileG * 256 + lane * 4;

  float4 cc0 = ((const float4*)(loadP + 0 * 256))[lane];
  float4 cc1 = ((const float4*)(loadP + 1 * 256))[lane];
  float4 cc2 = ((const float4*)(loadP + 2 * 256))[lane];
  float4 cc3 = ((const float4*)(loadP + 3 * 256))[lane];
  float4 cc4 = ((const float4*)(loadP + 4 * 256))[lane];
  float4 cc5 = ((const float4*)(loadP + 5 * 256))[lane];
  float4 cc6 = ((const float4*)(loadP + 6 * 256))[lane];
  float4 cc7 = ((const float4*)(loadP + 7 * 256))[lane];
  loadP += 8 * 256;

  float edgeVec = INF, lvPrev = INF;
  float up0 = 0.f, up1 = 0.f, up2 = 0.f, up3 = 0.f;
  float dpp1 = INF, dpp2 = INF;
  float fin0 = INF, fin1 = INF, fin2 = INF, fin3 = INF;
  float ebuf[8];

#define BLOCKHEAD()                                                           \
  {                                                                           \
    if (W > 0) {                                                              \
      if (sb < N_) {                                                          \
        const int tgt = sb + 7;                                               \
        while (vProg[W - 1] < tgt) {}                                         \
        asm volatile("" ::: "memory");                                        \
        lvPrev = rdlane(edgeVec, 7);                                          \
        edgeVec = ring[W - 1][(sb + lane) & 1023];                            \
      }                                                                       \
    } else if (hasCarry) {                                                    \
      lvPrev = rdlane(edgeVec, 7);                                            \
      if (sb < N_) edgeVec = cring[(sb + lane) & 1023];                       \
    }                                                                         \
  }

#define DPSTEP(KK, CCV, ROW0, FIN)                                            \
  {                                                                           \
    const float lv = rdlane(edgeVec, (KK));                                   \
    const float left = (lane == 0) ? lv : dpp1;                               \
    const float diag = (lane == 0) ? lvPrev : dpp2;                           \
    lvPrev = lv;                                                              \
    float m0 = fminf(up0, left);                                              \
    float bv0 = fminf(diag, m0);                                              \
    unsigned int pk = (diag <= m0) ? 0u : ((up0 <= left) ? 1u : 2u);          \
    if (ROW0) bv0 = (sb + (KK) == lane) ? 0.f : bv0;                          \
    const float D0 = CCV.x + bv0;                                             \
    float m1 = fminf(up1, D0);                                                \
    float bv1 = fminf(up0, m1);                                               \
    pk |= ((up0 <= m1) ? 0u : ((up1 <= D0) ? 1u : 2u)) << 2;                  \
    if (ROW0) bv1 = (sb + (KK) == lane) ? 0.f : bv1;                          \
    const float D1 = CCV.y + bv1;                                             \
    float m2 = fminf(up2, D1);                                                \
    float bv2 = fminf(up1, m2);                                               \
    pk |= ((up1 <= m2) ? 0u : ((up2 <= D1) ? 1u : 2u)) << 4;                  \
    if (ROW0) bv2 = (sb + (KK) == lane) ? 0.f : bv2;                          \
    const float D2 = CCV.z + bv2;                                             \
    float m3 = fminf(up3, D2);                                                \
    float bv3 = fminf(up2, m3);                                               \
    pk |= ((up2 <= m3) ? 0u : ((up3 <= D2) ? 1u : 2u)) << 6;                  \
    if (ROW0) bv3 = (sb + (KK) == lane) ? 0.f : bv3;                          \
    const float D3 = CCV.w + bv3;                                             \
    ebuf[(KK)] = D3;                                                          \
    if ((KK) & 1) {                                                           \
      pk16 |= pk << 8;                                                        \
      decP[((KK) >> 1) * 64] = (unsigned short)pk16;                          \
    } else {                                                                  \
      pk16 = pk;                                                              \
    }                                                                         \
    if (FIN) {                                                                \
      const bool lr = (sb + (KK) == 1023 + lane);                             \
      fin0 = lr ? D0 : fin0; fin1 = lr ? D1 : fin1;                           \
      fin2 = lr ? D2 : fin2; fin3 = lr ? D3 : fin3;                           \
    }                                                                         \
    const float sh = wave_shr1(D3);                                           \
    dpp2 = dpp1; dpp1 = sh;                                                   \
    up0 = D0; up1 = D1; up2 = D2; up3 = D3;                                   \
    CCV = ((const float4*)(loadP + (KK) * 256))[lane];                        \
  }

#define BLOCKEND()                                                            \
  {                                                                           \
    const int r0 = sb - 63;                                                   \
    if (W < 3) {                                                              \
      if (lane == 63 && r0 > -8 && r0 < N_) {                                 \
        _Pragma("unroll") for (int k = 0; k < 8; ++k) {                       \
          const int r = r0 + k;                                               \
          if ((unsigned)r < (unsigned)N_) ring[W][r] = ebuf[k];               \
        }                                                                     \
        __builtin_amdgcn_s_waitcnt(0xC07F);                                   \
        vProg[W] = r0 + 7;                                                    \
      }                                                                       \
    } else if (chunk < 3) {                                                   \
      if (lane == 63 && r0 > -8 && r0 < N_) {                                 \
        _Pragma("unroll") for (int k = 0; k < 8; ++k) {                       \
          const int r = r0 + k;                                               \
          if ((unsigned)r < (unsigned)N_) carryB[r] = ebuf[k];                \
        }                                                                     \
      }                                                                       \
    }                                                                         \
    loadP += 8 * 256;                                                         \
    decP += 256;                                                              \
  }

#define STEP8(R0, FN)                                                         \
  DPSTEP(0, cc0, R0, FN) DPSTEP(1, cc1, R0, FN) DPSTEP(2, cc2, R0, FN)        \
  DPSTEP(3, cc3, R0, FN) DPSTEP(4, cc4, R0, FN) DPSTEP(5, cc5, R0, FN)        \
  DPSTEP(6, cc6, R0, FN) DPSTEP(7, cc7, R0, FN)

  int sb = 0;
  for (; sb < 64; sb += 8) {   // prologue: row-0 selects live
    BLOCKHEAD();
    unsigned int pk16;
    STEP8(1, 0)
    BLOCKEND();
  }
  for (; sb < 1016; sb += 8) { // main
    BLOCKHEAD();
    unsigned int pk16;
    STEP8(0, 0)
    BLOCKEND();
  }
  for (; sb < 1088; sb += 8) { // epilogue: fin captures
    BLOCKHEAD();
    unsigned int pk16;
    STEP8(0, 1)
    BLOCKEND();
  }
#undef DPSTEP
#undef STEP8
#undef BLOCKHEAD
#undef BLOCKEND

  float mv = fin0; int mj = jbase;
  if (fin1 < mv) { mv = fin1; mj = jbase + 1; }
  if (fin2 < mv) { mv = fin2; mj = jbase + 2; }
  if (fin3 < mv) { mv = fin3; mj = jbase + 3; }
#pragma unroll
  for (int off = 32; off > 0; off >>= 1) {
    const float ov = __shfl_down(mv, off);
    const int oj = __shfl_down(mj, off);
    if (ov < mv || (ov == mv && oj < mj)) { mv = ov; mj = oj; }
  }
  if (lane == 0) { redV[W] = mv; redJ[W] = mj; }
  __syncthreads();
  if (t == 0) {
    float bm = redV[0]; int bj = redJ[0];
#pragma unroll
    for (int w = 1; w < 4; ++w)
      if (redV[w] < bm) { bm = redV[w]; bj = redJ[w]; }
    partV[b * 4 + chunk] = bm;
    partJ[b * 4 + chunk] = bj;
  }
}

// ---------------------------------------------------------------------------
// Backtrack over skewed ushort-packed dec. Byte for (row r, quad q):
// tile=q>>6, l=q&63, s=r+l -> tile*TSB + (s>>1)*128 + l*2 + (s&1).
//
// R1 rewrite: the old per-lane scattered global byte loads (96 serialized
// full-latency loads per window) are replaced by a cooperative coalesced
// uint4 stage of the needed dec region (<=3 tiles x 64 p-rows x 128B = 24KB)
// into LDS, then per-lane byte extraction from LDS. Stage uses an XOR
// swizzle (byte bits[6:4] ^= p-row&7) because the natural extraction
// pattern (fixed l, varying p-row across lanes) is a 32-way bank conflict.
// ---------------------------------------------------------------------------
__global__ __launch_bounds__(64) void backtrack_kernel(
    const unsigned char* __restrict__ dec, const float* __restrict__ partV,
    const int* __restrict__ partJ, int nch, const float* __restrict__ y_t,
    float* __restrict__ w_vs, float* __restrict__ cost_out) {
  const int b = blockIdx.x;
  const int lane = threadIdx.x;
  __shared__ unsigned int stage[3 * 2048];          // 24 KB staged dec window
  __shared__ unsigned short tab[64][BTQ_ * 4 + 2];  // run-compressed decisions
  __shared__ int st_i, st_j;
  __shared__ int jrow[65];
  const unsigned char* db = dec + (size_t)b * 16 * TSB_;
  const float* yt = y_t + b * M_;
  float* wv = w_vs + b * N_;

  if (lane == 0) {
    float bc = finf(); int bj = 0;
    for (int c = 0; c < nch; ++c) {
      const float v = partV[b * nch + c];
      const int j = partJ[b * nch + c];
      if (v < bc) { bc = v; bj = j; }
    }
    cost_out[b] = bc;
    st_i = N_ - 1;
    st_j = bj;
    wv[N_ - 1] = yt[bj];
  }
  for (;;) {
    __syncthreads();
    const int i = st_i, j = st_j;
    if (i <= 0) break;
    const int qj = j >> 2;
    int qlo = qj - (BTQ_ - 1);
    if (qlo < 0) qlo = 0;
    const int Tbase = qlo >> 6;
    int plo = (i - 63) >> 1;
    if (plo < 0) plo = 0;   // i<=1023 => plo<=480, plo+63<=543=SPAIR_-1

    // --- cooperative coalesced stage: 3 tiles x 64 p-rows x 128B ---
#pragma unroll
    for (int tt = 0; tt < 3; ++tt) {
      int T = Tbase + tt;
      if (T > 15) T = 15;  // duplicate tile 15; never read for that tt
      const uint4* src =
          (const uint4*)(db + (size_t)T * TSB_ + (size_t)plo * 128);
#pragma unroll
      for (int v = 0; v < 8; ++v) {
        const int wb = tt * 8192 + (v * 64 + lane) * 16;
        const int sw = wb ^ (((wb >> 7) & 7) << 4);  // bank swizzle
        *(uint4*)((char*)stage + sw) = src[v * 64 + lane];
      }
    }
    __syncthreads();

    const int r = i - lane;
    if (r >= 1) {
      const unsigned char* sb8 = (const unsigned char*)stage;
      unsigned char wr[BTQ_];
#pragma unroll
      for (int k = 0; k < BTQ_; ++k) {
        const int q = qlo + k;
        const int tt = (q >> 6) - Tbase;
        const int l = q & 63;
        const int s = r + l;
        int idx = tt * 8192 + ((s >> 1) - plo) * 128 + l * 2 + (s & 1);
        idx ^= ((idx >> 7) & 7) << 4;  // matching bank swizzle
        wr[k] = sb8[idx];
      }
      unsigned short run = 0xFFFF;  // stuck sentinel
#pragma unroll
      for (int k = 0; k < BTQ_; ++k) {
        const unsigned int byte = wr[k];
#pragma unroll
        for (int cs = 0; cs < 4; ++cs) {
          const unsigned int code = (byte >> (2 * cs)) & 3u;
          const int c = 4 * k + cs;
          const unsigned short v =
              (code != 2u) ? (unsigned short)((c << 2) | code) : run;
          tab[lane][c] = v;
          run = v;
        }
      }
    }
    __syncthreads();
    if (lane == 0) {
      const int base = qlo << 2;
      int rr = i, cj = j;
      while (rr >= 1 && (i - rr) < 64) {
        const int l = i - rr;
        const int c = cj - base;
        if (c < 0) break;
        const unsigned short v = tab[l][c];
        if (v == 0xFFFF) { cj = base - 1; break; }
        const int e = v >> 2;
        const int ce = v & 3;
        cj = base + e - (ce == 0 ? 1 : 0);
        --rr;
        jrow[i - rr] = cj;
      }
      st_i = rr;
      st_j = cj;
    }
    __syncthreads();
    const int cnt = i - st_i;
    if (lane < cnt) wv[i - 1 - lane] = yt[jrow[lane + 1]];
  }
}

// ---------------------------------------------------------------------------
extern "C" void kernel_launch(void* const* d_in, const int* in_sizes, int n_in,
                              void* d_out, int out_size, void* d_ws, size_t ws_size,
                              hipStream_t stream) {
  const float* x = (const float*)d_in[0];
  const float* y = (const float*)d_in[1];
  const float* x_t = (const float*)d_in[2];
  const float* y_t = (const float*)d_in[3];

  float* out_cost = (float*)d_out;      // [B_]
  float* out_wts = out_cost + B_;       // [B_][N_]
  float* out_wvs = out_wts + B_ * N_;   // [B_][N_]

  const size_t csBytes = (size_t)B_ * 4 * SROWSP_ * 256 * 4;  // ~71.9 MB
  const size_t decBytes = (size_t)B_ * 16 * TSB_;             // ~17.8 MB
  const size_t x2Bytes = (size_t)B_ * N_ * 4;

  char* ws = (char*)d_ws;
  float* Cs = (float*)ws;
  unsigned char* dec = (unsigned char*)(ws + csBytes);
  float* x2 = (float*)(ws + csBytes + decBytes);
  float* carryA = (float*)(ws + csBytes + decBytes + x2Bytes);
  float* carryB = carryA + B_ * N_;
  float* partV = carryB + B_ * N_;
  int* partJ = (int*)(partV + B_ * 4);

  prep_kernel<<<dim3((B_ * N_) / 256), 256, 0, stream>>>(x, x_t, x2, out_wts);

  float* cbuf[2] = {carryA, carryB};
  for (int c = 0; c < 4; ++c) {
    gemm_kernel<<<dim3(4, N_ / 128, B_), 256, 0, stream>>>(x, y, x2, Cs,
                                                           c * 1024);
    const float* cin = cbuf[(c + 1) & 1];
    float* cout = cbuf[c & 1];
    dtw_dp<<<dim3(B_), 256, 0, stream>>>(Cs, dec, cin, cout, partV, partJ, c,
                                         c > 0 ? 1 : 0);
  }

  backtrack_kernel<<<dim3(B_), 64, 0, stream>>>(dec, partV, partJ, 4, y_t,
                                                out_wvs, out_cost);
}

// Round 3
// 1173.162 us; speedup vs baseline: 1.2422x; 1.1739x over previous
//
#include <hip/hip_runtime.h>

#define B_ 16
#define N_ 1024
#define M_ 4096
#define D_ 64
#define SROWS_ (N_ + 63)        // 1087 valid skewed steps per tile
#define SROWSP_ (SROWS_ + 9)    // padded stride (refill overrun safety)
#define SPAIR_ 544              // step-pairs per tile
#define TSB_ ((size_t)SPAIR_ * 128)  // dec bytes per tile (69632)
#define BTQ_ 96                 // backtrack window quads (384 cells)

__device__ __forceinline__ float finf() { return __builtin_inff(); }

__device__ __forceinline__ float wave_shr1(float x) {
  return __int_as_float(__builtin_amdgcn_update_dpp(
      0, __float_as_int(x), 0x138, 0xF, 0xF, false));
}
__device__ __forceinline__ float rdlane(float v, int l) {
  return __int_as_float(__builtin_amdgcn_readlane(__float_as_int(v), l));
}

// ---------------------------------------------------------------------------
__global__ void prep_kernel(const float* __restrict__ x,
                            const float* __restrict__ x_t,
                            float* __restrict__ x2,
                            float* __restrict__ w_ts_out) {
  int id = blockIdx.x * blockDim.x + threadIdx.x;
  const float4* xr = (const float4*)(x + (size_t)id * D_);
  float s = 0.f;
#pragma unroll
  for (int e = 0; e < D_ / 4; ++e) {
    float4 v = xr[e];
    s += v.x * v.x + v.y * v.y + v.z * v.z + v.w * v.w;
  }
  x2[id] = s;
  w_ts_out[id] = x_t[id];
}

// ---------------------------------------------------------------------------
// GEMM v2 (R2): register/LDS-tiled, exact same per-cell arithmetic as v1.
// Block tile: 32 rows x 256 cols. 256 threads = 64 col-groups x 4 row-groups.
// Thread: 4 cols {cg, cg+64, cg+128, cg+192} x 8 rows, acc[8][4].
// y tile (256 cols x 64 D) + y2 staged in LDS; x tile (32 rows x 64 D) in
// LDS (wave-uniform reads broadcast for free, unlike vector L1 reads).
// d-accumulation order per cell is identical to v1 (kb-outer, e-asc, xyzw),
// expressions copied verbatim -> bit-identical C (absmax must stay 0.0).
// ---------------------------------------------------------------------------
__global__ __launch_bounds__(256) void gemm_kernel(
    const float* __restrict__ x, const float* __restrict__ y,
    const float* __restrict__ x2, float* __restrict__ Cs, int chunkBase) {
  const int b = blockIdx.z;
  const int tile = blockIdx.x;
  const int t = threadIdx.x;
  const int cg = t & 63;
  const int rg = t >> 6;
  const int ibeg = blockIdx.y * 32;
  float* CsT = Cs + (size_t)(b * 4 + tile) * SROWSP_ * 256;

  __shared__ float4 ylds[16 * 256];  // [e][col], 64KB
  __shared__ float4 xlds[16 * 32];   // [e][row], 8KB
  __shared__ float y2lds[256];

  // --- stage y col t: exact same load + y2 expression as v1 ---
  {
    const int j = chunkBase + tile * 256 + t;
    const float4* yrow = (const float4*)(y + ((size_t)b * M_ + j) * D_);
    float4 yr[16];
#pragma unroll
    for (int e = 0; e < 16; ++e) yr[e] = yrow[e];
    float y2 = 0.f;
#pragma unroll
    for (int e = 0; e < 16; ++e)
      y2 += yr[e].x * yr[e].x + yr[e].y * yr[e].y + yr[e].z * yr[e].z +
            yr[e].w * yr[e].w;
    y2lds[t] = y2;
#pragma unroll
    for (int e = 0; e < 16; ++e) ylds[e * 256 + t] = yr[e];
  }
  // --- stage x rows ibeg..ibeg+31 (threads 0..127, 4 float4 each) ---
  if (t < 128) {
    const int row = t >> 2;
    const int part = t & 3;
    const float4* xr = (const float4*)(x + ((size_t)b * N_ + ibeg + row) * D_);
#pragma unroll
    for (int k = 0; k < 4; ++k) {
      const int e = part * 4 + k;
      xlds[e * 32 + row] = xr[e];
    }
  }
  __syncthreads();

  const int r0 = rg * 8;
  float acc[8][4];
#pragma unroll
  for (int r = 0; r < 8; ++r)
#pragma unroll
    for (int c = 0; c < 4; ++c) acc[r][c] = 0.f;

#pragma unroll
  for (int kb = 0; kb < 4; ++kb) {
    float4 yf[4][4];  // [c][ee]
#pragma unroll
    for (int c = 0; c < 4; ++c)
#pragma unroll
      for (int ee = 0; ee < 4; ++ee)
        yf[c][ee] = ylds[(kb * 4 + ee) * 256 + cg + 64 * c];
#pragma unroll
    for (int r = 0; r < 8; ++r) {
      float4 xv[4];
#pragma unroll
      for (int ee = 0; ee < 4; ++ee)
        xv[ee] = xlds[(kb * 4 + ee) * 32 + r0 + r];
#pragma unroll
      for (int ee = 0; ee < 4; ++ee) {
#pragma unroll
        for (int c = 0; c < 4; ++c) {
          acc[r][c] += xv[ee].x * yf[c][ee].x + xv[ee].y * yf[c][ee].y +
                       xv[ee].z * yf[c][ee].z + xv[ee].w * yf[c][ee].w;
        }
      }
    }
  }

  // --- epilogue: exact same combine expression as v1 ---
#pragma unroll
  for (int r = 0; r < 8; ++r) {
    const int i = ibeg + r0 + r;
    const float xx = x2[b * N_ + i];
#pragma unroll
    for (int c = 0; c < 4; ++c) {
      const int ct = cg + 64 * c;
      const int l = ct >> 2;
      CsT[(size_t)(i + l) * 256 + ct] = xx + y2lds[ct] - 2.f * acc[r][c];
    }
  }
}

// ---------------------------------------------------------------------------
// Systolic DP, one batch per 256-thread WG (1 wave/SIMD). Wave W owns a
// 256-col tile; lane l owns 4 cols; step s => row i = s - lane. DECOUPLED
// pipeline: full-column (1024-entry) LDS edge buffer per wave pair, producer
// publishes batched (8 rows, lane 63, block end), consumer polls once/block
// with ~8 blocks of slack. dec packed as ushort (2 steps/store).
// ---------------------------------------------------------------------------
__global__ __launch_bounds__(256) void dtw_dp(
    const float* __restrict__ Cs, unsigned char* __restrict__ dec,
    const float* __restrict__ carryIn, float* __restrict__ carryOut,
    float* __restrict__ partV, int* __restrict__ partJ,
    int chunk, int hasCarry) {
  const int b = blockIdx.x;
  const int t = threadIdx.x;
  const int lane = t & 63;
  const int W = t >> 6;

  __shared__ float ring[3][1024];
  __shared__ float cring[1024];
  __shared__ int prog[3];
  __shared__ float redV[4];
  __shared__ int redJ[4];
  volatile int* vProg = prog;

  if (t < 3) prog[t] = -1;
  const float* cIn = carryIn + b * N_;
  if (hasCarry) ((float4*)cring)[t] = ((const float4*)cIn)[t];
  __syncthreads();

  const float INF = finf();
  const float* loadP = Cs + (size_t)(b * 4 + W) * SROWSP_ * 256;
  const int tileG = chunk * 4 + W;
  unsigned short* decP =
      (unsigned short*)(dec + (size_t)(b * 16 + tileG) * TSB_) + lane;
  float* carryB = carryOut + b * N_;
  const int jbase = tileG * 256 + lane * 4;

  float4 cc0 = ((const float4*)(loadP + 0 * 256))[lane];
  float4 cc1 = ((const float4*)(loadP + 1 * 256))[lane];
  float4 cc2 = ((const float4*)(loadP + 2 * 256))[lane];
  float4 cc3 = ((const float4*)(loadP + 3 * 256))[lane];
  float4 cc4 = ((const float4*)(loadP + 4 * 256))[lane];
  float4 cc5 = ((const float4*)(loadP + 5 * 256))[lane];
  float4 cc6 = ((const float4*)(loadP + 6 * 256))[lane];
  float4 cc7 = ((const float4*)(loadP + 7 * 256))[lane];
  loadP += 8 * 256;

  float edgeVec = INF, lvPrev = INF;
  float up0 = 0.f, up1 = 0.f, up2 = 0.f, up3 = 0.f;
  float dpp1 = INF, dpp2 = INF;
  float fin0 = INF, fin1 = INF, fin2 = INF, fin3 = INF;
  float ebuf[8];

#define BLOCKHEAD()                                                           \
  {                                                                           \
    if (W > 0) {                                                              \
      if (sb < N_) {                                                          \
        const int tgt = sb + 7;                                               \
        while (vProg[W - 1] < tgt) {}                                         \
        asm volatile("" ::: "memory");                                        \
        lvPrev = rdlane(edgeVec, 7);                                          \
        edgeVec = ring[W - 1][(sb + lane) & 1023];                            \
      }                                                                       \
    } else if (hasCarry) {                                                    \
      lvPrev = rdlane(edgeVec, 7);                                            \
      if (sb < N_) edgeVec = cring[(sb + lane) & 1023];                       \
    }                                                                         \
  }

#define DPSTEP(KK, CCV, ROW0, FIN)                                            \
  {                                                                           \
    const float lv = rdlane(edgeVec, (KK));                                   \
    const float left = (lane == 0) ? lv : dpp1;                               \
    const float diag = (lane == 0) ? lvPrev : dpp2;                           \
    lvPrev = lv;                                                              \
    float m0 = fminf(up0, left);                                              \
    float bv0 = fminf(diag, m0);                                              \
    unsigned int pk = (diag <= m0) ? 0u : ((up0 <= left) ? 1u : 2u);          \
    if (ROW0) bv0 = (sb + (KK) == lane) ? 0.f : bv0;                          \
    const float D0 = CCV.x + bv0;                                             \
    float m1 = fminf(up1, D0);                                                \
    float bv1 = fminf(up0, m1);                                               \
    pk |= ((up0 <= m1) ? 0u : ((up1 <= D0) ? 1u : 2u)) << 2;                  \
    if (ROW0) bv1 = (sb + (KK) == lane) ? 0.f : bv1;                          \
    const float D1 = CCV.y + bv1;                                             \
    float m2 = fminf(up2, D1);                                                \
    float bv2 = fminf(up1, m2);                                               \
    pk |= ((up1 <= m2) ? 0u : ((up2 <= D1) ? 1u : 2u)) << 4;                  \
    if (ROW0) bv2 = (sb + (KK) == lane) ? 0.f : bv2;                          \
    const float D2 = CCV.z + bv2;                                             \
    float m3 = fminf(up3, D2);                                                \
    float bv3 = fminf(up2, m3);                                               \
    pk |= ((up2 <= m3) ? 0u : ((up3 <= D2) ? 1u : 2u)) << 6;                  \
    if (ROW0) bv3 = (sb + (KK) == lane) ? 0.f : bv3;                          \
    const float D3 = CCV.w + bv3;                                             \
    ebuf[(KK)] = D3;                                                          \
    if ((KK) & 1) {                                                           \
      pk16 |= pk << 8;                                                        \
      decP[((KK) >> 1) * 64] = (unsigned short)pk16;                          \
    } else {                                                                  \
      pk16 = pk;                                                              \
    }                                                                         \
    if (FIN) {                                                                \
      const bool lr = (sb + (KK) == 1023 + lane);                             \
      fin0 = lr ? D0 : fin0; fin1 = lr ? D1 : fin1;                           \
      fin2 = lr ? D2 : fin2; fin3 = lr ? D3 : fin3;                           \
    }                                                                         \
    const float sh = wave_shr1(D3);                                           \
    dpp2 = dpp1; dpp1 = sh;                                                   \
    up0 = D0; up1 = D1; up2 = D2; up3 = D3;                                   \
    CCV = ((const float4*)(loadP + (KK) * 256))[lane];                        \
  }

#define BLOCKEND()                                                            \
  {                                                                           \
    const int r0 = sb - 63;                                                   \
    if (W < 3) {                                                              \
      if (lane == 63 && r0 > -8 && r0 < N_) {                                 \
        _Pragma("unroll") for (int k = 0; k < 8; ++k) {                       \
          const int r = r0 + k;                                               \
          if ((unsigned)r < (unsigned)N_) ring[W][r] = ebuf[k];               \
        }                                                                     \
        __builtin_amdgcn_s_waitcnt(0xC07F);                                   \
        vProg[W] = r0 + 7;                                                    \
      }                                                                       \
    } else if (chunk < 3) {                                                   \
      if (lane == 63 && r0 > -8 && r0 < N_) {                                 \
        _Pragma("unroll") for (int k = 0; k < 8; ++k) {                       \
          const int r = r0 + k;                                               \
          if ((unsigned)r < (unsigned)N_) carryB[r] = ebuf[k];                \
        }                                                                     \
      }                                                                       \
    }                                                                         \
    loadP += 8 * 256;                                                         \
    decP += 256;                                                              \
  }

#define STEP8(R0, FN)                                                         \
  DPSTEP(0, cc0, R0, FN) DPSTEP(1, cc1, R0, FN) DPSTEP(2, cc2, R0, FN)        \
  DPSTEP(3, cc3, R0, FN) DPSTEP(4, cc4, R0, FN) DPSTEP(5, cc5, R0, FN)        \
  DPSTEP(6, cc6, R0, FN) DPSTEP(7, cc7, R0, FN)

  int sb = 0;
  for (; sb < 64; sb += 8) {   // prologue: row-0 selects live
    BLOCKHEAD();
    unsigned int pk16;
    STEP8(1, 0)
    BLOCKEND();
  }
  for (; sb < 1016; sb += 8) { // main
    BLOCKHEAD();
    unsigned int pk16;
    STEP8(0, 0)
    BLOCKEND();
  }
  for (; sb < 1088; sb += 8) { // epilogue: fin captures
    BLOCKHEAD();
    unsigned int pk16;
    STEP8(0, 1)
    BLOCKEND();
  }
#undef DPSTEP
#undef STEP8
#undef BLOCKHEAD
#undef BLOCKEND

  float mv = fin0; int mj = jbase;
  if (fin1 < mv) { mv = fin1; mj = jbase + 1; }
  if (fin2 < mv) { mv = fin2; mj = jbase + 2; }
  if (fin3 < mv) { mv = fin3; mj = jbase + 3; }
#pragma unroll
  for (int off = 32; off > 0; off >>= 1) {
    const float ov = __shfl_down(mv, off);
    const int oj = __shfl_down(mj, off);
    if (ov < mv || (ov == mv && oj < mj)) { mv = ov; mj = oj; }
  }
  if (lane == 0) { redV[W] = mv; redJ[W] = mj; }
  __syncthreads();
  if (t == 0) {
    float bm = redV[0]; int bj = redJ[0];
#pragma unroll
    for (int w = 1; w < 4; ++w)
      if (redV[w] < bm) { bm = redV[w]; bj = redJ[w]; }
    partV[b * 4 + chunk] = bm;
    partJ[b * 4 + chunk] = bj;
  }
}

// ---------------------------------------------------------------------------
// Backtrack over skewed ushort-packed dec. Byte for (row r, quad q):
// tile=q>>6, l=q&63, s=r+l -> tile*TSB + (s>>1)*128 + l*2 + (s&1).
// R1: cooperative coalesced uint4 stage of the dec window into LDS (with
// XOR bank swizzle), then per-lane byte extraction from LDS.
// ---------------------------------------------------------------------------
__global__ __launch_bounds__(64) void backtrack_kernel(
    const unsigned char* __restrict__ dec, const float* __restrict__ partV,
    const int* __restrict__ partJ, int nch, const float* __restrict__ y_t,
    float* __restrict__ w_vs, float* __restrict__ cost_out) {
  const int b = blockIdx.x;
  const int lane = threadIdx.x;
  __shared__ unsigned int stage[3 * 2048];          // 24 KB staged dec window
  __shared__ unsigned short tab[64][BTQ_ * 4 + 2];  // run-compressed decisions
  __shared__ int st_i, st_j;
  __shared__ int jrow[65];
  const unsigned char* db = dec + (size_t)b * 16 * TSB_;
  const float* yt = y_t + b * M_;
  float* wv = w_vs + b * N_;

  if (lane == 0) {
    float bc = finf(); int bj = 0;
    for (int c = 0; c < nch; ++c) {
      const float v = partV[b * nch + c];
      const int j = partJ[b * nch + c];
      if (v < bc) { bc = v; bj = j; }
    }
    cost_out[b] = bc;
    st_i = N_ - 1;
    st_j = bj;
    wv[N_ - 1] = yt[bj];
  }
  for (;;) {
    __syncthreads();
    const int i = st_i, j = st_j;
    if (i <= 0) break;
    const int qj = j >> 2;
    int qlo = qj - (BTQ_ - 1);
    if (qlo < 0) qlo = 0;
    const int Tbase = qlo >> 6;
    int plo = (i - 63) >> 1;
    if (plo < 0) plo = 0;   // i<=1023 => plo<=480, plo+63<=543=SPAIR_-1

    // --- cooperative coalesced stage: 3 tiles x 64 p-rows x 128B ---
#pragma unroll
    for (int tt = 0; tt < 3; ++tt) {
      int T = Tbase + tt;
      if (T > 15) T = 15;  // duplicate tile 15; never read for that tt
      const uint4* src =
          (const uint4*)(db + (size_t)T * TSB_ + (size_t)plo * 128);
#pragma unroll
      for (int v = 0; v < 8; ++v) {
        const int wb = tt * 8192 + (v * 64 + lane) * 16;
        const int sw = wb ^ (((wb >> 7) & 7) << 4);  // bank swizzle
        *(uint4*)((char*)stage + sw) = src[v * 64 + lane];
      }
    }
    __syncthreads();

    const int r = i - lane;
    if (r >= 1) {
      const unsigned char* sb8 = (const unsigned char*)stage;
      unsigned char wr[BTQ_];
#pragma unroll
      for (int k = 0; k < BTQ_; ++k) {
        const int q = qlo + k;
        const int tt = (q >> 6) - Tbase;
        const int l = q & 63;
        const int s = r + l;
        int idx = tt * 8192 + ((s >> 1) - plo) * 128 + l * 2 + (s & 1);
        idx ^= ((idx >> 7) & 7) << 4;  // matching bank swizzle
        wr[k] = sb8[idx];
      }
      unsigned short run = 0xFFFF;  // stuck sentinel
#pragma unroll
      for (int k = 0; k < BTQ_; ++k) {
        const unsigned int byte = wr[k];
#pragma unroll
        for (int cs = 0; cs < 4; ++cs) {
          const unsigned int code = (byte >> (2 * cs)) & 3u;
          const int c = 4 * k + cs;
          const unsigned short v =
              (code != 2u) ? (unsigned short)((c << 2) | code) : run;
          tab[lane][c] = v;
          run = v;
        }
      }
    }
    __syncthreads();
    if (lane == 0) {
      const int base = qlo << 2;
      int rr = i, cj = j;
      while (rr >= 1 && (i - rr) < 64) {
        const int l = i - rr;
        const int c = cj - base;
        if (c < 0) break;
        const unsigned short v = tab[l][c];
        if (v == 0xFFFF) { cj = base - 1; break; }
        const int e = v >> 2;
        const int ce = v & 3;
        cj = base + e - (ce == 0 ? 1 : 0);
        --rr;
        jrow[i - rr] = cj;
      }
      st_i = rr;
      st_j = cj;
    }
    __syncthreads();
    const int cnt = i - st_i;
    if (lane < cnt) wv[i - 1 - lane] = yt[jrow[lane + 1]];
  }
}

// ---------------------------------------------------------------------------
extern "C" void kernel_launch(void* const* d_in, const int* in_sizes, int n_in,
                              void* d_out, int out_size, void* d_ws, size_t ws_size,
                              hipStream_t stream) {
  const float* x = (const float*)d_in[0];
  const float* y = (const float*)d_in[1];
  const float* x_t = (const float*)d_in[2];
  const float* y_t = (const float*)d_in[3];

  float* out_cost = (float*)d_out;      // [B_]
  float* out_wts = out_cost + B_;       // [B_][N_]
  float* out_wvs = out_wts + B_ * N_;   // [B_][N_]

  const size_t csBytes = (size_t)B_ * 4 * SROWSP_ * 256 * 4;  // ~71.9 MB
  const size_t decBytes = (size_t)B_ * 16 * TSB_;             // ~17.8 MB
  const size_t x2Bytes = (size_t)B_ * N_ * 4;

  char* ws = (char*)d_ws;
  float* Cs = (float*)ws;
  unsigned char* dec = (unsigned char*)(ws + csBytes);
  float* x2 = (float*)(ws + csBytes + decBytes);
  float* carryA = (float*)(ws + csBytes + decBytes + x2Bytes);
  float* carryB = carryA + B_ * N_;
  float* partV = carryB + B_ * N_;
  int* partJ = (int*)(partV + B_ * 4);

  prep_kernel<<<dim3((B_ * N_) / 256), 256, 0, stream>>>(x, x_t, x2, out_wts);

  float* cbuf[2] = {carryA, carryB};
  for (int c = 0; c < 4; ++c) {
    gemm_kernel<<<dim3(4, N_ / 32, B_), 256, 0, stream>>>(x, y, x2, Cs,
                                                          c * 1024);
    const float* cin = cbuf[(c + 1) & 1];
    float* cout = cbuf[c & 1];
    dtw_dp<<<dim3(B_), 256, 0, stream>>>(Cs, dec, cin, cout, partV, partJ, c,
                                         c > 0 ? 1 : 0);
  }

  backtrack_kernel<<<dim3(B_), 64, 0, stream>>>(dec, partV, partJ, 4, y_t,
                                                out_wvs, out_cost);
}